// Round 4
// baseline (701.320 us; speedup 1.0000x reference)
//
#include <hip/hip_runtime.h>
#include <hip/hip_bf16.h>
#include <math.h>

// ---------------------------------------------------------------------------
// GAT: 2x GATConv(heads=1) + global mean pool + FC(64->2)
// R3: bf16 feature storage (halve gather traffic), no-max softmax
//     (logits bounded ~|30| << 87 overflow limit), 16-node GEMM blocks.
//   init -> hist(deg) -> scan_p1/p2/p3 -> scatter(srcs)
//   -> gemm1(+logits) -> aggregate_csr -> gemm2(+b1,leaky,+logits)
//   -> aggregate_csr -> pool(run-length) -> fc
// ---------------------------------------------------------------------------

#define SCAN_T 256
#define SCAN_I 4
#define SCAN_IPB (SCAN_T * SCAN_I)   // 1024 nodes per block

__device__ __forceinline__ void atomAddF(float* a, float v) {
    unsafeAtomicAdd(a, v);   // hw global_atomic_add_f32 on gfx950
}

__device__ __forceinline__ unsigned short f2bf(float v) {
    unsigned int b = __float_as_uint(v);
    b += 0x7FFFu + ((b >> 16) & 1u);   // round-to-nearest-even
    return (unsigned short)(b >> 16);
}

// --- init: deg=1 (self loop), pooled=0, cnt=0 -------------------------------
__global__ __launch_bounds__(256) void init_all(int* __restrict__ deg,
                                                float* __restrict__ pooled,
                                                float* __restrict__ cnt,
                                                int n, int G) {
    int i = blockIdx.x * 256 + threadIdx.x;
    if (i < n) deg[i] = 1;             // every node gets a self-loop
    if (i < G * 64) pooled[i] = 0.0f;
    if (i < G) cnt[i] = 0.0f;
}

// --- histogram of incoming-edge counts --------------------------------------
__global__ __launch_bounds__(256) void hist_deg(const int* __restrict__ ei,
                                                int E, int* __restrict__ deg) {
    int i = blockIdx.x * 256 + threadIdx.x;
    if (i >= E) return;
    atomicAdd(&deg[ei[E + i]], 1);
}

// --- scan phase 1: per-block degree sums ------------------------------------
__global__ __launch_bounds__(SCAN_T) void scan_p1(const int* __restrict__ deg,
                                                  int* __restrict__ bsums, int n) {
    int b = blockIdx.x, t = threadIdx.x;
    int base = b * SCAN_IPB + t * SCAN_I;
    int s = 0;
#pragma unroll
    for (int k = 0; k < SCAN_I; k++) {
        int i = base + k;
        if (i < n) s += deg[i];
    }
    __shared__ int red[SCAN_T];
    red[t] = s;
    __syncthreads();
    for (int o = SCAN_T / 2; o; o >>= 1) {
        if (t < o) red[t] += red[t + o];
        __syncthreads();
    }
    if (t == 0) bsums[b] = red[0];
}

// --- scan phase 2: exclusive scan of block sums (B <= 256) ------------------
__global__ __launch_bounds__(256) void scan_p2(int* __restrict__ bsums, int B) {
    __shared__ int tmp[256];
    int t = threadIdx.x;
    int v = (t < B) ? bsums[t] : 0;
    tmp[t] = v;
    __syncthreads();
    for (int o = 1; o < 256; o <<= 1) {
        int u = (t >= o) ? tmp[t - o] : 0;
        __syncthreads();
        tmp[t] += u;
        __syncthreads();
    }
    if (t < B) bsums[t] = tmp[t] - v;   // exclusive
}

// --- scan phase 3: write rowptr, self-loop srcs, cursor ---------------------
__global__ __launch_bounds__(SCAN_T) void scan_p3(int* __restrict__ deg,
                                                  const int* __restrict__ bsums,
                                                  int* __restrict__ rowptr,
                                                  int* __restrict__ srcs,
                                                  int n, int tot) {
    int b = blockIdx.x, t = threadIdx.x;
    int base = b * SCAN_IPB + t * SCAN_I;
    int d[SCAN_I];
    int s = 0;
#pragma unroll
    for (int k = 0; k < SCAN_I; k++) {
        int i = base + k;
        d[k] = (i < n) ? deg[i] : 0;
        s += d[k];
    }
    __shared__ int tmp[SCAN_T];
    tmp[t] = s;
    __syncthreads();
    for (int o = 1; o < SCAN_T; o <<= 1) {
        int u = (t >= o) ? tmp[t - o] : 0;
        __syncthreads();
        tmp[t] += u;
        __syncthreads();
    }
    int run = bsums[b] + tmp[t] - s;    // exclusive offset for this thread
#pragma unroll
    for (int k = 0; k < SCAN_I; k++) {
        int i = base + k;
        if (i >= n) break;
        rowptr[i] = run;
        srcs[run] = i;      // self-loop at slot 0 of segment
        deg[i] = run + 1;   // deg[] becomes scatter cursor
        run += d[k];
    }
    if (b == 0 && t == 0) rowptr[n] = tot;
}

// --- scatter real edges into CSR --------------------------------------------
__global__ __launch_bounds__(256) void scatter_edges(const int* __restrict__ ei,
                                                     int E,
                                                     int* __restrict__ cursor,
                                                     int* __restrict__ srcs) {
    int i = blockIdx.x * 256 + threadIdx.x;
    if (i >= E) return;
    int s = ei[i];
    int d = ei[E + i];
    int pos = atomicAdd(&cursor[d], 1);
    srcs[pos] = s;
}

// --- node GEMM: h = act(x + bias_in) @ W (bf16 out); logits per node --------
// 16 nodes/block: 4 waves x 4 nodes/wave. W staged once per block.
template <int IN_DIM>
__global__ __launch_bounds__(256) void node_gemm(const float* __restrict__ x,
                                                 const float* __restrict__ W,
                                                 const float* __restrict__ a_src,
                                                 const float* __restrict__ a_dst,
                                                 const float* __restrict__ bias_in,
                                                 float slope_in,
                                                 unsigned short* __restrict__ h16,
                                                 float* __restrict__ al_s,
                                                 float* __restrict__ al_d,
                                                 int n) {
    __shared__ float Ws[IN_DIM * 64];
    __shared__ float xs[4][4][IN_DIM];
    int t = threadIdx.x;
    for (int idx = t; idx < IN_DIM * 64; idx += 256) Ws[idx] = W[idx];
    int wave = t >> 6, lane = t & 63;
    int node0 = blockIdx.x * 16 + wave * 4;
#pragma unroll
    for (int k = 0; k < 4; k++) {
        int node = node0 + k;
        if (node >= n) break;
        for (int d = lane; d < IN_DIM; d += 64) {
            float v = x[(size_t)node * IN_DIM + d];
            if (bias_in) {
                v += bias_in[d];
                v = (v >= 0.0f) ? v : slope_in * v;
            }
            xs[wave][k][d] = v;
        }
    }
    __syncthreads();
    if (node0 >= n) return;
    float sum[4] = {0.0f, 0.0f, 0.0f, 0.0f};
    for (int d = 0; d < IN_DIM; d++) {
        float w = Ws[d * 64 + lane];
#pragma unroll
        for (int k = 0; k < 4; k++) sum[k] += xs[wave][k][d] * w;
    }
    float asv = a_src[lane], adv = a_dst[lane];
#pragma unroll
    for (int k = 0; k < 4; k++) {
        int node = node0 + k;
        if (node >= n) break;
        h16[(size_t)node * 64 + lane] = f2bf(sum[k]);
        float vs = sum[k] * asv;
        float vd = sum[k] * adv;
#pragma unroll
        for (int o = 32; o; o >>= 1) {
            vs += __shfl_xor(vs, o);
            vd += __shfl_xor(vd, o);
        }
        if (lane == 0) { al_s[node] = vs; al_d[node] = vd; }
    }
}

// --- CSR aggregate: no-max segment softmax + bf16 gather, 16 lanes/node -----
__global__ __launch_bounds__(256) void gat_aggregate(const int* __restrict__ rowptr,
                                                     const int* __restrict__ srcs,
                                                     const float* __restrict__ als,
                                                     const float* __restrict__ ald,
                                                     const unsigned short* __restrict__ h16,
                                                     float* __restrict__ hout,
                                                     int n) {
    int t = threadIdx.x;
    int sub = t >> 4, lane = t & 15;
    int node = blockIdx.x * 16 + sub;
    if (node >= n) return;
    int beg = rowptr[node], end = rowptr[node + 1];
    float aldv = ald[node];

    // pass 1: sum of exp (no max shift: |e| << 87, cannot overflow)
    float sm = 0.0f;
    for (int j = beg + lane; j < end; j += 16) {
        float e = als[srcs[j]] + aldv;
        e = (e >= 0.0f) ? e : 0.2f * e;
        sm += __expf(e);
    }
#pragma unroll
    for (int o = 8; o; o >>= 1) sm += __shfl_xor(sm, o);
    float inv = 1.0f / (sm + 1e-16f);

    // pass 2: weighted feature gather (lane = 4 features, bf16x4 per load)
    float4 acc = make_float4(0.0f, 0.0f, 0.0f, 0.0f);
    for (int j = beg; j < end; j++) {
        int s = srcs[j];
        float e = als[s] + aldv;
        e = (e >= 0.0f) ? e : 0.2f * e;
        float w = __expf(e) * inv;
        uint2 q = *(const uint2*)(h16 + (size_t)s * 64 + lane * 4);
        acc.x += w * __uint_as_float(q.x << 16);
        acc.y += w * __uint_as_float(q.x & 0xFFFF0000u);
        acc.z += w * __uint_as_float(q.y << 16);
        acc.w += w * __uint_as_float(q.y & 0xFFFF0000u);
    }
    *(float4*)(hout + (size_t)node * 64 + lane * 4) = acc;
}

// --- pooling: run-length accumulate over sorted batch, then one atomic ------
__global__ __launch_bounds__(256) void pool_run(const float* __restrict__ hout,
                                                const float* __restrict__ b2,
                                                const int* __restrict__ batch,
                                                float* __restrict__ pooled,
                                                float* __restrict__ cnt,
                                                int n) {
    int t = threadIdx.x;
    int wv = blockIdx.x * 4 + (t >> 6);
    int lane = t & 63;
    int start = wv * 64;
    if (start >= n) return;
    int end = min(start + 64, n);
    float bb = b2[lane];
    int gcur = batch[start];
    float acc = 0.0f;
    int rl = 0;
    for (int node = start; node < end; node++) {
        int g = batch[node];
        if (g != gcur) {
            atomAddF(&pooled[gcur * 64 + lane], acc);
            if (lane == 0) atomAddF(&cnt[gcur], (float)rl);
            acc = 0.0f; rl = 0; gcur = g;
        }
        acc += hout[(size_t)node * 64 + lane] + bb;
        rl++;
    }
    atomAddF(&pooled[gcur * 64 + lane], acc);
    if (lane == 0) atomAddF(&cnt[gcur], (float)rl);
}

// --- final FC: out[g] = (pooled[g]/max(cnt,1)) @ fcW + fcb ------------------
__global__ __launch_bounds__(64) void final_fc(const float* __restrict__ pooled,
                                               const float* __restrict__ cnt,
                                               const float* __restrict__ fcW,
                                               const float* __restrict__ fcb,
                                               float* __restrict__ out) {
    int g = blockIdx.x;
    int lane = threadIdx.x;
    float c = cnt[g];
    c = (c > 1.0f) ? c : 1.0f;
    float p = pooled[g * 64 + lane] / c;
    float s0 = p * fcW[lane * 2 + 0];
    float s1 = p * fcW[lane * 2 + 1];
#pragma unroll
    for (int o = 32; o; o >>= 1) {
        s0 += __shfl_xor(s0, o);
        s1 += __shfl_xor(s1, o);
    }
    if (lane == 0) {
        out[g * 2 + 0] = s0 + fcb[0];
        out[g * 2 + 1] = s1 + fcb[1];
    }
}

extern "C" void kernel_launch(void* const* d_in, const int* in_sizes, int n_in,
                              void* d_out, int out_size, void* d_ws, size_t ws_size,
                              hipStream_t stream) {
    const float* x    = (const float*)d_in[0];
    const int*   ei   = (const int*)d_in[1];
    const int*   batch= (const int*)d_in[2];
    const float* W1   = (const float*)d_in[3];
    const float* as1  = (const float*)d_in[4];
    const float* ad1  = (const float*)d_in[5];
    const float* b1   = (const float*)d_in[6];
    const float* W2   = (const float*)d_in[7];
    const float* as2  = (const float*)d_in[8];
    const float* ad2  = (const float*)d_in[9];
    const float* b2   = (const float*)d_in[10];
    const float* fcW  = (const float*)d_in[11];
    const float* fcb  = (const float*)d_in[12];
    float* out = (float*)d_out;

    const int N = in_sizes[2];       // 100000
    const int E = in_sizes[1] / 2;   // 1600000
    const int G = out_size / 2;      // 256
    const int tot = E + N;
    const int B = (N + SCAN_IPB - 1) / SCAN_IPB;   // scan blocks (98 for 100K)

    float* ws     = (float*)d_ws;
    float* bufO   = ws;                          // N*64 fp32 (aggregate out)
    float* als    = bufO + (size_t)N * 64;       // N
    float* ald    = als + N;                     // N
    float* pooled = ald + N;                     // G*64
    float* cnt    = pooled + (size_t)G * 64;     // G
    int*   deg    = (int*)(cnt + G);             // N  (becomes cursor)
    int*   rowptr = deg + N;                     // N+1
    int*   srcs   = rowptr + N + 1;              // E+N
    int*   bsums  = srcs + tot;                  // B
    unsigned short* bufH16 = (unsigned short*)(bsums + B + 1);  // N*64 bf16

    dim3 b256(256);
    int gN    = (N + 255) / 256;
    int gE    = (E + 255) / 256;
    int gNode = (N + 15) / 16;
    int gAgg  = (N + 15) / 16;
    int gPool = ((N + 63) / 64 + 3) / 4;

    // ---- CSR build (edge_index only — shared by both layers) ----
    init_all<<<gN, b256, 0, stream>>>(deg, pooled, cnt, N, G);
    hist_deg<<<gE, b256, 0, stream>>>(ei, E, deg);
    scan_p1<<<B, SCAN_T, 0, stream>>>(deg, bsums, N);
    scan_p2<<<1, 256, 0, stream>>>(bsums, B);
    scan_p3<<<B, SCAN_T, 0, stream>>>(deg, bsums, rowptr, srcs, N, tot);
    scatter_edges<<<gE, b256, 0, stream>>>(ei, E, deg, srcs);

    // ---- layer 1 ----
    node_gemm<72><<<gNode, b256, 0, stream>>>(x, W1, as1, ad1, nullptr, 0.0f,
                                              bufH16, als, ald, N);
    gat_aggregate<<<gAgg, b256, 0, stream>>>(rowptr, srcs, als, ald, bufH16, bufO, N);

    // ---- layer 2 (input = leaky(bufO + b1, 0.01)) ----
    node_gemm<64><<<gNode, b256, 0, stream>>>(bufO, W2, as2, ad2, b1, 0.01f,
                                              bufH16, als, ald, N);
    gat_aggregate<<<gAgg, b256, 0, stream>>>(rowptr, srcs, als, ald, bufH16, bufO, N);

    // ---- pool + fc ----
    pool_run<<<gPool, b256, 0, stream>>>(bufO, b2, batch, pooled, cnt, N);
    final_fc<<<G, 64, 0, stream>>>(pooled, cnt, fcW, fcb, out);
}

// Round 5
// 524.598 us; speedup vs baseline: 1.3369x; 1.3369x over previous
//
#include <hip/hip_runtime.h>
#include <hip/hip_bf16.h>
#include <math.h>

// ---------------------------------------------------------------------------
// GAT: 2x GATConv(heads=1) + global mean pool + FC(64->2)
// R4: tiled node GEMM (64 nodes x 64 cols/block, 4x4 register tiles)
//     replacing the R3 low-occupancy 4-node/wave version (145us -> ~15us).
//     bf16 h storage + no-max softmax retained (absmax 2e-3 < 6.7e-3).
// ---------------------------------------------------------------------------

#define SCAN_T 256
#define SCAN_I 4
#define SCAN_IPB (SCAN_T * SCAN_I)   // 1024 nodes per block

__device__ __forceinline__ void atomAddF(float* a, float v) {
    unsafeAtomicAdd(a, v);   // hw global_atomic_add_f32 on gfx950
}

__device__ __forceinline__ unsigned int f2bf(float v) {
    unsigned int b = __float_as_uint(v);
    b += 0x7FFFu + ((b >> 16) & 1u);   // round-to-nearest-even
    return b >> 16;
}

// --- init: deg=1 (self loop), pooled=0, cnt=0 -------------------------------
__global__ __launch_bounds__(256) void init_all(int* __restrict__ deg,
                                                float* __restrict__ pooled,
                                                float* __restrict__ cnt,
                                                int n, int G) {
    int i = blockIdx.x * 256 + threadIdx.x;
    if (i < n) deg[i] = 1;             // every node gets a self-loop
    if (i < G * 64) pooled[i] = 0.0f;
    if (i < G) cnt[i] = 0.0f;
}

// --- histogram of incoming-edge counts --------------------------------------
__global__ __launch_bounds__(256) void hist_deg(const int* __restrict__ ei,
                                                int E, int* __restrict__ deg) {
    int i = blockIdx.x * 256 + threadIdx.x;
    if (i >= E) return;
    atomicAdd(&deg[ei[E + i]], 1);
}

// --- scan phase 1: per-block degree sums ------------------------------------
__global__ __launch_bounds__(SCAN_T) void scan_p1(const int* __restrict__ deg,
                                                  int* __restrict__ bsums, int n) {
    int b = blockIdx.x, t = threadIdx.x;
    int base = b * SCAN_IPB + t * SCAN_I;
    int s = 0;
#pragma unroll
    for (int k = 0; k < SCAN_I; k++) {
        int i = base + k;
        if (i < n) s += deg[i];
    }
    __shared__ int red[SCAN_T];
    red[t] = s;
    __syncthreads();
    for (int o = SCAN_T / 2; o; o >>= 1) {
        if (t < o) red[t] += red[t + o];
        __syncthreads();
    }
    if (t == 0) bsums[b] = red[0];
}

// --- scan phase 2: exclusive scan of block sums (B <= 256) ------------------
__global__ __launch_bounds__(256) void scan_p2(int* __restrict__ bsums, int B) {
    __shared__ int tmp[256];
    int t = threadIdx.x;
    int v = (t < B) ? bsums[t] : 0;
    tmp[t] = v;
    __syncthreads();
    for (int o = 1; o < 256; o <<= 1) {
        int u = (t >= o) ? tmp[t - o] : 0;
        __syncthreads();
        tmp[t] += u;
        __syncthreads();
    }
    if (t < B) bsums[t] = tmp[t] - v;   // exclusive
}

// --- scan phase 3: write rowptr, self-loop srcs, cursor ---------------------
__global__ __launch_bounds__(SCAN_T) void scan_p3(int* __restrict__ deg,
                                                  const int* __restrict__ bsums,
                                                  int* __restrict__ rowptr,
                                                  int* __restrict__ srcs,
                                                  int n, int tot) {
    int b = blockIdx.x, t = threadIdx.x;
    int base = b * SCAN_IPB + t * SCAN_I;
    int d[SCAN_I];
    int s = 0;
#pragma unroll
    for (int k = 0; k < SCAN_I; k++) {
        int i = base + k;
        d[k] = (i < n) ? deg[i] : 0;
        s += d[k];
    }
    __shared__ int tmp[SCAN_T];
    tmp[t] = s;
    __syncthreads();
    for (int o = 1; o < SCAN_T; o <<= 1) {
        int u = (t >= o) ? tmp[t - o] : 0;
        __syncthreads();
        tmp[t] += u;
        __syncthreads();
    }
    int run = bsums[b] + tmp[t] - s;    // exclusive offset for this thread
#pragma unroll
    for (int k = 0; k < SCAN_I; k++) {
        int i = base + k;
        if (i >= n) break;
        rowptr[i] = run;
        srcs[run] = i;      // self-loop at slot 0 of segment
        deg[i] = run + 1;   // deg[] becomes scatter cursor
        run += d[k];
    }
    if (b == 0 && t == 0) rowptr[n] = tot;
}

// --- scatter real edges into CSR --------------------------------------------
__global__ __launch_bounds__(256) void scatter_edges(const int* __restrict__ ei,
                                                     int E,
                                                     int* __restrict__ cursor,
                                                     int* __restrict__ srcs) {
    int i = blockIdx.x * 256 + threadIdx.x;
    if (i >= E) return;
    int s = ei[i];
    int d = ei[E + i];
    int pos = atomicAdd(&cursor[d], 1);
    srcs[pos] = s;
}

// --- tiled node GEMM: 64 nodes x 64 cols per block, 4x4 per thread ----------
// h = act(x + bias_in) @ W  -> bf16; logits al_s/al_d per node.
// xs staged k-major (transposed) so the inner loop is 2x ds_read_b128 + 16 FMA.
template <int IN_DIM>
__global__ __launch_bounds__(256) void node_gemm(const float* __restrict__ x,
                                                 const float* __restrict__ W,
                                                 const float* __restrict__ a_src,
                                                 const float* __restrict__ a_dst,
                                                 const float* __restrict__ bias_in,
                                                 float slope_in,
                                                 unsigned short* __restrict__ h16,
                                                 float* __restrict__ al_s,
                                                 float* __restrict__ al_d,
                                                 int n) {
    __shared__ float Ws[IN_DIM * 64];
    __shared__ float xs[IN_DIM][64];   // [k][node] — conflict-free both ways
    int t = threadIdx.x;
    int nbase = blockIdx.x * 64;

    // stage W (contiguous, float4)
    for (int idx = t; idx < IN_DIM * 16; idx += 256)
        ((float4*)Ws)[idx] = ((const float4*)W)[idx];
    // stage x transposed: lane sticks to one node, walks k in steps of 4
    for (int idx = t; idx < IN_DIM * 64; idx += 256) {
        int node = nbase + (idx & 63);
        int k = idx >> 6;
        float v = 0.0f;
        if (node < n) {
            v = x[(size_t)node * IN_DIM + k];
            if (bias_in) {
                v += bias_in[k];
                v = (v >= 0.0f) ? v : slope_in * v;
            }
        }
        xs[k][idx & 63] = v;
    }
    __syncthreads();

    int cg = t & 15;    // col group: cols 4cg..4cg+3
    int ng = t >> 4;    // node group: nodes 4ng..4ng+3 (wave covers 16 nodes)
    float acc[4][4] = {};
#pragma unroll 8
    for (int k = 0; k < IN_DIM; k++) {
        float4 xv = *(const float4*)&xs[k][ng * 4];
        float4 wv = *(const float4*)&Ws[k * 64 + cg * 4];
        float xa[4] = {xv.x, xv.y, xv.z, xv.w};
        float wa[4] = {wv.x, wv.y, wv.z, wv.w};
#pragma unroll
        for (int i = 0; i < 4; i++)
#pragma unroll
            for (int j = 0; j < 4; j++)
                acc[i][j] += xa[i] * wa[j];
    }

    float4 as4 = *(const float4*)(a_src + cg * 4);
    float4 ad4 = *(const float4*)(a_dst + cg * 4);
#pragma unroll
    for (int i = 0; i < 4; i++) {
        int node = nbase + ng * 4 + i;
        // bf16 store: 4 cols packed into 8 B
        if (node < n) {
            uint2 p;
            p.x = f2bf(acc[i][0]) | (f2bf(acc[i][1]) << 16);
            p.y = f2bf(acc[i][2]) | (f2bf(acc[i][3]) << 16);
            *(uint2*)(h16 + (size_t)node * 64 + cg * 4) = p;
        }
        float vs = acc[i][0] * as4.x + acc[i][1] * as4.y +
                   acc[i][2] * as4.z + acc[i][3] * as4.w;
        float vd = acc[i][0] * ad4.x + acc[i][1] * ad4.y +
                   acc[i][2] * ad4.z + acc[i][3] * ad4.w;
#pragma unroll
        for (int o = 8; o; o >>= 1) {
            vs += __shfl_xor(vs, o);
            vd += __shfl_xor(vd, o);
        }
        if (cg == 0 && node < n) { al_s[node] = vs; al_d[node] = vd; }
    }
}

// --- CSR aggregate: no-max segment softmax + bf16 gather, 16 lanes/node -----
__global__ __launch_bounds__(256) void gat_aggregate(const int* __restrict__ rowptr,
                                                     const int* __restrict__ srcs,
                                                     const float* __restrict__ als,
                                                     const float* __restrict__ ald,
                                                     const unsigned short* __restrict__ h16,
                                                     float* __restrict__ hout,
                                                     int n) {
    int t = threadIdx.x;
    int sub = t >> 4, lane = t & 15;
    int node = blockIdx.x * 16 + sub;
    if (node >= n) return;
    int beg = rowptr[node], end = rowptr[node + 1];
    float aldv = ald[node];

    // pass 1: sum of exp (no max shift: |e| << 87, cannot overflow)
    float sm = 0.0f;
    for (int j = beg + lane; j < end; j += 16) {
        float e = als[srcs[j]] + aldv;
        e = (e >= 0.0f) ? e : 0.2f * e;
        sm += __expf(e);
    }
#pragma unroll
    for (int o = 8; o; o >>= 1) sm += __shfl_xor(sm, o);
    float inv = 1.0f / (sm + 1e-16f);

    // pass 2: weighted feature gather (lane = 4 features, bf16x4 per load)
    float4 acc = make_float4(0.0f, 0.0f, 0.0f, 0.0f);
    for (int j = beg; j < end; j++) {
        int s = srcs[j];
        float e = als[s] + aldv;
        e = (e >= 0.0f) ? e : 0.2f * e;
        float w = __expf(e) * inv;
        uint2 q = *(const uint2*)(h16 + (size_t)s * 64 + lane * 4);
        acc.x += w * __uint_as_float(q.x << 16);
        acc.y += w * __uint_as_float(q.x & 0xFFFF0000u);
        acc.z += w * __uint_as_float(q.y << 16);
        acc.w += w * __uint_as_float(q.y & 0xFFFF0000u);
    }
    *(float4*)(hout + (size_t)node * 64 + lane * 4) = acc;
}

// --- pooling: run-length accumulate over sorted batch, then one atomic ------
__global__ __launch_bounds__(256) void pool_run(const float* __restrict__ hout,
                                                const float* __restrict__ b2,
                                                const int* __restrict__ batch,
                                                float* __restrict__ pooled,
                                                float* __restrict__ cnt,
                                                int n) {
    int t = threadIdx.x;
    int wv = blockIdx.x * 4 + (t >> 6);
    int lane = t & 63;
    int start = wv * 64;
    if (start >= n) return;
    int end = min(start + 64, n);
    float bb = b2[lane];
    int gcur = batch[start];
    float acc = 0.0f;
    int rl = 0;
    for (int node = start; node < end; node++) {
        int g = batch[node];
        if (g != gcur) {
            atomAddF(&pooled[gcur * 64 + lane], acc);
            if (lane == 0) atomAddF(&cnt[gcur], (float)rl);
            acc = 0.0f; rl = 0; gcur = g;
        }
        acc += hout[(size_t)node * 64 + lane] + bb;
        rl++;
    }
    atomAddF(&pooled[gcur * 64 + lane], acc);
    if (lane == 0) atomAddF(&cnt[gcur], (float)rl);
}

// --- final FC: out[g] = (pooled[g]/max(cnt,1)) @ fcW + fcb ------------------
__global__ __launch_bounds__(64) void final_fc(const float* __restrict__ pooled,
                                               const float* __restrict__ cnt,
                                               const float* __restrict__ fcW,
                                               const float* __restrict__ fcb,
                                               float* __restrict__ out) {
    int g = blockIdx.x;
    int lane = threadIdx.x;
    float c = cnt[g];
    c = (c > 1.0f) ? c : 1.0f;
    float p = pooled[g * 64 + lane] / c;
    float s0 = p * fcW[lane * 2 + 0];
    float s1 = p * fcW[lane * 2 + 1];
#pragma unroll
    for (int o = 32; o; o >>= 1) {
        s0 += __shfl_xor(s0, o);
        s1 += __shfl_xor(s1, o);
    }
    if (lane == 0) {
        out[g * 2 + 0] = s0 + fcb[0];
        out[g * 2 + 1] = s1 + fcb[1];
    }
}

extern "C" void kernel_launch(void* const* d_in, const int* in_sizes, int n_in,
                              void* d_out, int out_size, void* d_ws, size_t ws_size,
                              hipStream_t stream) {
    const float* x    = (const float*)d_in[0];
    const int*   ei   = (const int*)d_in[1];
    const int*   batch= (const int*)d_in[2];
    const float* W1   = (const float*)d_in[3];
    const float* as1  = (const float*)d_in[4];
    const float* ad1  = (const float*)d_in[5];
    const float* b1   = (const float*)d_in[6];
    const float* W2   = (const float*)d_in[7];
    const float* as2  = (const float*)d_in[8];
    const float* ad2  = (const float*)d_in[9];
    const float* b2   = (const float*)d_in[10];
    const float* fcW  = (const float*)d_in[11];
    const float* fcb  = (const float*)d_in[12];
    float* out = (float*)d_out;

    const int N = in_sizes[2];       // 100000
    const int E = in_sizes[1] / 2;   // 1600000
    const int G = out_size / 2;      // 256
    const int tot = E + N;
    const int B = (N + SCAN_IPB - 1) / SCAN_IPB;   // scan blocks (98 for 100K)

    float* ws     = (float*)d_ws;
    float* bufO   = ws;                          // N*64 fp32 (aggregate out)
    float* als    = bufO + (size_t)N * 64;       // N
    float* ald    = als + N;                     // N
    float* pooled = ald + N;                     // G*64
    float* cnt    = pooled + (size_t)G * 64;     // G
    int*   deg    = (int*)(cnt + G);             // N  (becomes cursor)
    int*   rowptr = deg + N;                     // N+1
    int*   srcs   = rowptr + N + 1;              // E+N
    int*   bsums  = srcs + tot;                  // B
    unsigned short* bufH16 = (unsigned short*)(bsums + B + 1);  // N*64 bf16

    dim3 b256(256);
    int gN    = (N + 255) / 256;
    int gE    = (E + 255) / 256;
    int gGemm = (N + 63) / 64;
    int gAgg  = (N + 15) / 16;
    int gPool = ((N + 63) / 64 + 3) / 4;

    // ---- CSR build (edge_index only — shared by both layers) ----
    init_all<<<gN, b256, 0, stream>>>(deg, pooled, cnt, N, G);
    hist_deg<<<gE, b256, 0, stream>>>(ei, E, deg);
    scan_p1<<<B, SCAN_T, 0, stream>>>(deg, bsums, N);
    scan_p2<<<1, 256, 0, stream>>>(bsums, B);
    scan_p3<<<B, SCAN_T, 0, stream>>>(deg, bsums, rowptr, srcs, N, tot);
    scatter_edges<<<gE, b256, 0, stream>>>(ei, E, deg, srcs);

    // ---- layer 1 ----
    node_gemm<72><<<gGemm, b256, 0, stream>>>(x, W1, as1, ad1, nullptr, 0.0f,
                                              bufH16, als, ald, N);
    gat_aggregate<<<gAgg, b256, 0, stream>>>(rowptr, srcs, als, ald, bufH16, bufO, N);

    // ---- layer 2 (input = leaky(bufO + b1, 0.01)) ----
    node_gemm<64><<<gGemm, b256, 0, stream>>>(bufO, W2, as2, ad2, b1, 0.01f,
                                              bufH16, als, ald, N);
    gat_aggregate<<<gAgg, b256, 0, stream>>>(rowptr, srcs, als, ald, bufH16, bufO, N);

    // ---- pool + fc ----
    pool_run<<<gPool, b256, 0, stream>>>(bufO, b2, batch, pooled, cnt, N);
    final_fc<<<G, 64, 0, stream>>>(pooled, cnt, fcW, fcb, out);
}

// Round 6
// 390.072 us; speedup vs baseline: 1.7979x; 1.3449x over previous
//
#include <hip/hip_runtime.h>
#include <hip/hip_bf16.h>
#include <math.h>

// ---------------------------------------------------------------------------
// GAT: 2x GATConv(heads=1) + global mean pool + FC(64->2)
// R5: bucket-partition CSR build replaces hist/scan/scatter.
//     Old scatter_edges: 104MB HBM writes (15x line amplification) ~125us +
//     hist_deg's 1.7M random atomics. New: partition into 391 dst-buckets
//     (256 nodes each) with LDS histograms + grouped pair writes, then
//     per-bucket CSR fill inside a ~17KB L2-resident window.
// Downstream (gemm/aggregate/pool/fc) unchanged from R4 winner.
// Assumes N <= 131072 (NB = ceil(N/256) <= 512). N=100000 here -> NB=391.
// ---------------------------------------------------------------------------

#define NPB 256          // nodes per bucket
#define EPB 4096         // edges per partition block (256 thr x 16)

__device__ __forceinline__ void atomAddF(float* a, float v) {
    unsafeAtomicAdd(a, v);   // hw global_atomic_add_f32 on gfx950
}

__device__ __forceinline__ unsigned int f2bf(float v) {
    unsigned int b = __float_as_uint(v);
    b += 0x7FFFu + ((b >> 16) & 1u);   // round-to-nearest-even
    return b >> 16;
}

// --- init: zero pooled, cnt, bucket_cnt -------------------------------------
__global__ __launch_bounds__(256) void init_all(float* __restrict__ pooled,
                                                float* __restrict__ cnt,
                                                int* __restrict__ bucket_cnt,
                                                int NB, int G) {
    int i = blockIdx.x * 256 + threadIdx.x;
    if (i < G * 64) pooled[i] = 0.0f;
    if (i < G) cnt[i] = 0.0f;
    if (i < NB) bucket_cnt[i] = 0;
}

// --- A1: bucket histogram (LDS-staged) --------------------------------------
__global__ __launch_bounds__(256) void bucket_hist(const int* __restrict__ ei,
                                                   int E, int NB,
                                                   int* __restrict__ bucket_cnt) {
    __shared__ int h[512];
    int t = threadIdx.x;
    for (int i = t; i < 512; i += 256) h[i] = 0;
    __syncthreads();
    int i0 = blockIdx.x * EPB;
#pragma unroll
    for (int k = 0; k < 16; k++) {
        int i = i0 + k * 256 + t;
        if (i < E) atomicAdd(&h[ei[E + i] >> 8], 1);
    }
    __syncthreads();
    for (int b = t; b < NB; b += 256)
        if (h[b]) atomicAdd(&bucket_cnt[b], h[b]);
}

// --- A2: exclusive scan of bucket counts (NB <= 512) ------------------------
__global__ __launch_bounds__(512) void scan_buckets(const int* __restrict__ cnt,
                                                    int* __restrict__ base,
                                                    int* __restrict__ cur, int NB) {
    __shared__ int tmp[512];
    int t = threadIdx.x;
    int v = (t < NB) ? cnt[t] : 0;
    tmp[t] = v;
    __syncthreads();
    for (int o = 1; o < 512; o <<= 1) {
        int u = (t >= o) ? tmp[t - o] : 0;
        __syncthreads();
        tmp[t] += u;
        __syncthreads();
    }
    if (t < NB) { int e = tmp[t] - v; base[t] = e; cur[t] = e; }
}

// --- A3: partition edges into dst-buckets (grouped pair writes) -------------
__global__ __launch_bounds__(256) void partition(const int* __restrict__ ei,
                                                 int E, int NB,
                                                 int* __restrict__ cur,
                                                 uint2* __restrict__ pairs) {
    __shared__ int h[512];
    __shared__ int bb[512];
    int t = threadIdx.x;
    for (int i = t; i < 512; i += 256) h[i] = 0;
    __syncthreads();
    int i0 = blockIdx.x * EPB;
    int s[16], bk[16], r[16];
#pragma unroll
    for (int k = 0; k < 16; k++) {
        int i = i0 + k * 256 + t;
        bk[k] = -1;
        if (i < E) {
            s[k] = ei[i];
            int d = ei[E + i];
            bk[k] = d >> 8;
            r[k] = atomicAdd(&h[bk[k]], 1);
            s[k] = s[k];
            // pack dst into the pair later; keep d via bk*256? need exact d:
            // store d in r high bits? simpler: recompute not possible. Keep d:
            // reuse an extra register array below.
        }
    }
    // we need dst too; redo loads cheaply (L1/L2-warm) to save registers
    __syncthreads();
    for (int b = t; b < NB; b += 256)
        bb[b] = h[b] ? atomicAdd(&cur[b], h[b]) : 0;
    __syncthreads();
#pragma unroll
    for (int k = 0; k < 16; k++) {
        if (bk[k] < 0) continue;
        int i = i0 + k * 256 + t;
        int d = ei[E + i];                 // warm reload
        pairs[bb[bk[k]] + r[k]] = make_uint2((unsigned)s[k], (unsigned)d);
    }
}

// --- B: per-bucket CSR fill (writes confined to ~17KB window) ---------------
__global__ __launch_bounds__(256) void build_csr(const uint2* __restrict__ pairs,
                                                 const int* __restrict__ cnt,
                                                 const int* __restrict__ base,
                                                 int n, int tot,
                                                 int* __restrict__ rowptr,
                                                 int* __restrict__ srcs) {
    int b = blockIdx.x, t = threadIdx.x;
    int d0 = b << 8;
    int nb = min(NPB, n - d0);
    int pbeg = base[b], pend = pbeg + cnt[b];
    int csr0 = pbeg + d0;   // pairs before + one self-loop per node before

    __shared__ int deg[NPB];
    __shared__ int cur[NPB];
    __shared__ int tmp[NPB];
    deg[t] = (t < nb) ? 1 : 0;   // self-loop
    __syncthreads();
    for (int j = pbeg + t; j < pend; j += 256)
        atomicAdd(&deg[pairs[j].y - d0], 1);
    __syncthreads();
    int v = deg[t];
    tmp[t] = v;
    __syncthreads();
    for (int o = 1; o < NPB; o <<= 1) {
        int u = (t >= o) ? tmp[t - o] : 0;
        __syncthreads();
        tmp[t] += u;
        __syncthreads();
    }
    int excl = tmp[t] - v;
    if (t < nb) {
        rowptr[d0 + t] = csr0 + excl;
        srcs[csr0 + excl] = d0 + t;   // self-loop at slot 0
        cur[t] = excl + 1;
    }
    __syncthreads();
    for (int j = pbeg + t; j < pend; j += 256) {
        uint2 p = pairs[j];
        int off = atomicAdd(&cur[p.y - d0], 1);
        srcs[csr0 + off] = (int)p.x;
    }
    if (b == 0 && t == 0) rowptr[n] = tot;
}

// --- tiled node GEMM: 64 nodes x 64 cols per block, 4x4 per thread ----------
template <int IN_DIM>
__global__ __launch_bounds__(256) void node_gemm(const float* __restrict__ x,
                                                 const float* __restrict__ W,
                                                 const float* __restrict__ a_src,
                                                 const float* __restrict__ a_dst,
                                                 const float* __restrict__ bias_in,
                                                 float slope_in,
                                                 unsigned short* __restrict__ h16,
                                                 float* __restrict__ al_s,
                                                 float* __restrict__ al_d,
                                                 int n) {
    __shared__ float Ws[IN_DIM * 64];
    __shared__ float xs[IN_DIM][64];   // [k][node] — conflict-free both ways
    int t = threadIdx.x;
    int nbase = blockIdx.x * 64;

    for (int idx = t; idx < IN_DIM * 16; idx += 256)
        ((float4*)Ws)[idx] = ((const float4*)W)[idx];
    for (int idx = t; idx < IN_DIM * 64; idx += 256) {
        int node = nbase + (idx & 63);
        int k = idx >> 6;
        float v = 0.0f;
        if (node < n) {
            v = x[(size_t)node * IN_DIM + k];
            if (bias_in) {
                v += bias_in[k];
                v = (v >= 0.0f) ? v : slope_in * v;
            }
        }
        xs[k][idx & 63] = v;
    }
    __syncthreads();

    int cg = t & 15;    // col group: cols 4cg..4cg+3
    int ng = t >> 4;    // node group: nodes 4ng..4ng+3
    float acc[4][4] = {};
#pragma unroll 8
    for (int k = 0; k < IN_DIM; k++) {
        float4 xv = *(const float4*)&xs[k][ng * 4];
        float4 wv = *(const float4*)&Ws[k * 64 + cg * 4];
        float xa[4] = {xv.x, xv.y, xv.z, xv.w};
        float wa[4] = {wv.x, wv.y, wv.z, wv.w};
#pragma unroll
        for (int i = 0; i < 4; i++)
#pragma unroll
            for (int j = 0; j < 4; j++)
                acc[i][j] += xa[i] * wa[j];
    }

    float4 as4 = *(const float4*)(a_src + cg * 4);
    float4 ad4 = *(const float4*)(a_dst + cg * 4);
#pragma unroll
    for (int i = 0; i < 4; i++) {
        int node = nbase + ng * 4 + i;
        if (node < n) {
            uint2 p;
            p.x = f2bf(acc[i][0]) | (f2bf(acc[i][1]) << 16);
            p.y = f2bf(acc[i][2]) | (f2bf(acc[i][3]) << 16);
            *(uint2*)(h16 + (size_t)node * 64 + cg * 4) = p;
        }
        float vs = acc[i][0] * as4.x + acc[i][1] * as4.y +
                   acc[i][2] * as4.z + acc[i][3] * as4.w;
        float vd = acc[i][0] * ad4.x + acc[i][1] * ad4.y +
                   acc[i][2] * ad4.z + acc[i][3] * ad4.w;
#pragma unroll
        for (int o = 8; o; o >>= 1) {
            vs += __shfl_xor(vs, o);
            vd += __shfl_xor(vd, o);
        }
        if (cg == 0 && node < n) { al_s[node] = vs; al_d[node] = vd; }
    }
}

// --- CSR aggregate: no-max segment softmax + bf16 gather, 16 lanes/node -----
__global__ __launch_bounds__(256) void gat_aggregate(const int* __restrict__ rowptr,
                                                     const int* __restrict__ srcs,
                                                     const float* __restrict__ als,
                                                     const float* __restrict__ ald,
                                                     const unsigned short* __restrict__ h16,
                                                     float* __restrict__ hout,
                                                     int n) {
    int t = threadIdx.x;
    int sub = t >> 4, lane = t & 15;
    int node = blockIdx.x * 16 + sub;
    if (node >= n) return;
    int beg = rowptr[node], end = rowptr[node + 1];
    float aldv = ald[node];

    float sm = 0.0f;
    for (int j = beg + lane; j < end; j += 16) {
        float e = als[srcs[j]] + aldv;
        e = (e >= 0.0f) ? e : 0.2f * e;
        sm += __expf(e);
    }
#pragma unroll
    for (int o = 8; o; o >>= 1) sm += __shfl_xor(sm, o);
    float inv = 1.0f / (sm + 1e-16f);

    float4 acc = make_float4(0.0f, 0.0f, 0.0f, 0.0f);
    for (int j = beg; j < end; j++) {
        int s = srcs[j];
        float e = als[s] + aldv;
        e = (e >= 0.0f) ? e : 0.2f * e;
        float w = __expf(e) * inv;
        uint2 q = *(const uint2*)(h16 + (size_t)s * 64 + lane * 4);
        acc.x += w * __uint_as_float(q.x << 16);
        acc.y += w * __uint_as_float(q.x & 0xFFFF0000u);
        acc.z += w * __uint_as_float(q.y << 16);
        acc.w += w * __uint_as_float(q.y & 0xFFFF0000u);
    }
    *(float4*)(hout + (size_t)node * 64 + lane * 4) = acc;
}

// --- pooling: run-length accumulate over sorted batch, then one atomic ------
__global__ __launch_bounds__(256) void pool_run(const float* __restrict__ hout,
                                                const float* __restrict__ b2,
                                                const int* __restrict__ batch,
                                                float* __restrict__ pooled,
                                                float* __restrict__ cnt,
                                                int n) {
    int t = threadIdx.x;
    int wv = blockIdx.x * 4 + (t >> 6);
    int lane = t & 63;
    int start = wv * 64;
    if (start >= n) return;
    int end = min(start + 64, n);
    float bb = b2[lane];
    int gcur = batch[start];
    float acc = 0.0f;
    int rl = 0;
    for (int node = start; node < end; node++) {
        int g = batch[node];
        if (g != gcur) {
            atomAddF(&pooled[gcur * 64 + lane], acc);
            if (lane == 0) atomAddF(&cnt[gcur], (float)rl);
            acc = 0.0f; rl = 0; gcur = g;
        }
        acc += hout[(size_t)node * 64 + lane] + bb;
        rl++;
    }
    atomAddF(&pooled[gcur * 64 + lane], acc);
    if (lane == 0) atomAddF(&cnt[gcur], (float)rl);
}

// --- final FC: out[g] = (pooled[g]/max(cnt,1)) @ fcW + fcb ------------------
__global__ __launch_bounds__(64) void final_fc(const float* __restrict__ pooled,
                                               const float* __restrict__ cnt,
                                               const float* __restrict__ fcW,
                                               const float* __restrict__ fcb,
                                               float* __restrict__ out) {
    int g = blockIdx.x;
    int lane = threadIdx.x;
    float c = cnt[g];
    c = (c > 1.0f) ? c : 1.0f;
    float p = pooled[g * 64 + lane] / c;
    float s0 = p * fcW[lane * 2 + 0];
    float s1 = p * fcW[lane * 2 + 1];
#pragma unroll
    for (int o = 32; o; o >>= 1) {
        s0 += __shfl_xor(s0, o);
        s1 += __shfl_xor(s1, o);
    }
    if (lane == 0) {
        out[g * 2 + 0] = s0 + fcb[0];
        out[g * 2 + 1] = s1 + fcb[1];
    }
}

extern "C" void kernel_launch(void* const* d_in, const int* in_sizes, int n_in,
                              void* d_out, int out_size, void* d_ws, size_t ws_size,
                              hipStream_t stream) {
    const float* x    = (const float*)d_in[0];
    const int*   ei   = (const int*)d_in[1];
    const int*   batch= (const int*)d_in[2];
    const float* W1   = (const float*)d_in[3];
    const float* as1  = (const float*)d_in[4];
    const float* ad1  = (const float*)d_in[5];
    const float* b1   = (const float*)d_in[6];
    const float* W2   = (const float*)d_in[7];
    const float* as2  = (const float*)d_in[8];
    const float* ad2  = (const float*)d_in[9];
    const float* b2   = (const float*)d_in[10];
    const float* fcW  = (const float*)d_in[11];
    const float* fcb  = (const float*)d_in[12];
    float* out = (float*)d_out;

    const int N = in_sizes[2];       // 100000
    const int E = in_sizes[1] / 2;   // 1600000
    const int G = out_size / 2;      // 256
    const int tot = E + N;
    const int NB = (N + NPB - 1) / NPB;   // 391 buckets

    // ws layout (pairs needs 8B alignment: placed right after bufO)
    float* ws     = (float*)d_ws;
    float* bufO   = ws;                          // N*64 fp32
    uint2* pairs  = (uint2*)(bufO + (size_t)N * 64);          // E uint2
    float* als    = (float*)(pairs + E);         // N
    float* ald    = als + N;                     // N
    float* pooled = ald + N;                     // G*64
    float* cnt    = pooled + (size_t)G * 64;     // G
    int*   rowptr = (int*)(cnt + G);             // N+1
    int*   srcs   = rowptr + N + 1;              // E+N
    int*   bcnt   = srcs + tot;                  // NB
    int*   bbase  = bcnt + NB;                   // NB
    int*   bcur   = bbase + NB;                  // NB
    unsigned short* bufH16 = (unsigned short*)(bcur + NB);    // N*64 bf16

    dim3 b256(256);
    int gInit = (max(G * 64, NB) + 255) / 256;
    int gPart = (E + EPB - 1) / EPB;
    int gGemm = (N + 63) / 64;
    int gAgg  = (N + 15) / 16;
    int gPool = ((N + 63) / 64 + 3) / 4;

    // ---- CSR build via bucket partition (edge_index only) ----
    init_all<<<gInit, b256, 0, stream>>>(pooled, cnt, bcnt, NB, G);
    bucket_hist<<<gPart, b256, 0, stream>>>(ei, E, NB, bcnt);
    scan_buckets<<<1, 512, 0, stream>>>(bcnt, bbase, bcur, NB);
    partition<<<gPart, b256, 0, stream>>>(ei, E, NB, bcur, pairs);
    build_csr<<<NB, b256, 0, stream>>>(pairs, bcnt, bbase, N, tot, rowptr, srcs);

    // ---- layer 1 ----
    node_gemm<72><<<gGemm, b256, 0, stream>>>(x, W1, as1, ad1, nullptr, 0.0f,
                                              bufH16, als, ald, N);
    gat_aggregate<<<gAgg, b256, 0, stream>>>(rowptr, srcs, als, ald, bufH16, bufO, N);

    // ---- layer 2 (input = leaky(bufO + b1, 0.01)) ----
    node_gemm<64><<<gGemm, b256, 0, stream>>>(bufO, W2, as2, ad2, b1, 0.01f,
                                              bufH16, als, ald, N);
    gat_aggregate<<<gAgg, b256, 0, stream>>>(rowptr, srcs, als, ald, bufH16, bufO, N);

    // ---- pool + fc ----
    pool_run<<<gPool, b256, 0, stream>>>(bufO, b2, batch, pooled, cnt, N);
    final_fc<<<G, 64, 0, stream>>>(pooled, cnt, fcW, fcb, out);
}

// Round 7
// 348.901 us; speedup vs baseline: 2.0101x; 1.1180x over previous
//
#include <hip/hip_runtime.h>
#include <hip/hip_bf16.h>
#include <math.h>

// ---------------------------------------------------------------------------
// GAT: 2x GATConv(heads=1) + global mean pool + FC(64->2)
// R6: single-pass fused aggregate. out = (sum exp(e)*h) / (sum exp(e)+eps)
//     -- normalization applied post-accumulation, so the separate exp-sum
//     pass is gone. 8 lanes/node (uint4 = 16B bf16x8 loads) doubles the
//     node-segments per wave; edge loop unrolled x4 with batched loads for
//     memory-level parallelism (R6 theory: aggregate was latency-bound,
//     31% HBM / 27% VALU / serial dependent gather chain).
// CSR build (R5 bucket partition) + tiled GEMM (R4) unchanged.
// ---------------------------------------------------------------------------

#define NPB 256          // nodes per bucket
#define EPB 4096         // edges per partition block (256 thr x 16)

__device__ __forceinline__ void atomAddF(float* a, float v) {
    unsafeAtomicAdd(a, v);   // hw global_atomic_add_f32 on gfx950
}

__device__ __forceinline__ unsigned int f2bf(float v) {
    unsigned int b = __float_as_uint(v);
    b += 0x7FFFu + ((b >> 16) & 1u);   // round-to-nearest-even
    return b >> 16;
}

// --- init: zero pooled, cnt, bucket_cnt -------------------------------------
__global__ __launch_bounds__(256) void init_all(float* __restrict__ pooled,
                                                float* __restrict__ cnt,
                                                int* __restrict__ bucket_cnt,
                                                int NB, int G) {
    int i = blockIdx.x * 256 + threadIdx.x;
    if (i < G * 64) pooled[i] = 0.0f;
    if (i < G) cnt[i] = 0.0f;
    if (i < NB) bucket_cnt[i] = 0;
}

// --- A1: bucket histogram (LDS-staged) --------------------------------------
__global__ __launch_bounds__(256) void bucket_hist(const int* __restrict__ ei,
                                                   int E, int NB,
                                                   int* __restrict__ bucket_cnt) {
    __shared__ int h[512];
    int t = threadIdx.x;
    for (int i = t; i < 512; i += 256) h[i] = 0;
    __syncthreads();
    int i0 = blockIdx.x * EPB;
#pragma unroll
    for (int k = 0; k < 16; k++) {
        int i = i0 + k * 256 + t;
        if (i < E) atomicAdd(&h[ei[E + i] >> 8], 1);
    }
    __syncthreads();
    for (int b = t; b < NB; b += 256)
        if (h[b]) atomicAdd(&bucket_cnt[b], h[b]);
}

// --- A2: exclusive scan of bucket counts (NB <= 512) ------------------------
__global__ __launch_bounds__(512) void scan_buckets(const int* __restrict__ cnt,
                                                    int* __restrict__ base,
                                                    int* __restrict__ cur, int NB) {
    __shared__ int tmp[512];
    int t = threadIdx.x;
    int v = (t < NB) ? cnt[t] : 0;
    tmp[t] = v;
    __syncthreads();
    for (int o = 1; o < 512; o <<= 1) {
        int u = (t >= o) ? tmp[t - o] : 0;
        __syncthreads();
        tmp[t] += u;
        __syncthreads();
    }
    if (t < NB) { int e = tmp[t] - v; base[t] = e; cur[t] = e; }
}

// --- A3: partition edges into dst-buckets (grouped pair writes) -------------
__global__ __launch_bounds__(256) void partition(const int* __restrict__ ei,
                                                 int E, int NB,
                                                 int* __restrict__ cur,
                                                 uint2* __restrict__ pairs) {
    __shared__ int h[512];
    __shared__ int bb[512];
    int t = threadIdx.x;
    for (int i = t; i < 512; i += 256) h[i] = 0;
    __syncthreads();
    int i0 = blockIdx.x * EPB;
    int s[16], bk[16], r[16];
#pragma unroll
    for (int k = 0; k < 16; k++) {
        int i = i0 + k * 256 + t;
        bk[k] = -1;
        if (i < E) {
            s[k] = ei[i];
            int d = ei[E + i];
            bk[k] = d >> 8;
            r[k] = atomicAdd(&h[bk[k]], 1);
        }
    }
    __syncthreads();
    for (int b = t; b < NB; b += 256)
        bb[b] = h[b] ? atomicAdd(&cur[b], h[b]) : 0;
    __syncthreads();
#pragma unroll
    for (int k = 0; k < 16; k++) {
        if (bk[k] < 0) continue;
        int i = i0 + k * 256 + t;
        int d = ei[E + i];                 // warm reload
        pairs[bb[bk[k]] + r[k]] = make_uint2((unsigned)s[k], (unsigned)d);
    }
}

// --- B: per-bucket CSR fill (writes confined to ~17KB window) ---------------
__global__ __launch_bounds__(256) void build_csr(const uint2* __restrict__ pairs,
                                                 const int* __restrict__ cnt,
                                                 const int* __restrict__ base,
                                                 int n, int tot,
                                                 int* __restrict__ rowptr,
                                                 int* __restrict__ srcs) {
    int b = blockIdx.x, t = threadIdx.x;
    int d0 = b << 8;
    int nb = min(NPB, n - d0);
    int pbeg = base[b], pend = pbeg + cnt[b];
    int csr0 = pbeg + d0;   // pairs before + one self-loop per node before

    __shared__ int deg[NPB];
    __shared__ int cur[NPB];
    __shared__ int tmp[NPB];
    deg[t] = (t < nb) ? 1 : 0;   // self-loop
    __syncthreads();
    for (int j = pbeg + t; j < pend; j += 256)
        atomicAdd(&deg[pairs[j].y - d0], 1);
    __syncthreads();
    int v = deg[t];
    tmp[t] = v;
    __syncthreads();
    for (int o = 1; o < NPB; o <<= 1) {
        int u = (t >= o) ? tmp[t - o] : 0;
        __syncthreads();
        tmp[t] += u;
        __syncthreads();
    }
    int excl = tmp[t] - v;
    if (t < nb) {
        rowptr[d0 + t] = csr0 + excl;
        srcs[csr0 + excl] = d0 + t;   // self-loop at slot 0
        cur[t] = excl + 1;
    }
    __syncthreads();
    for (int j = pbeg + t; j < pend; j += 256) {
        uint2 p = pairs[j];
        int off = atomicAdd(&cur[p.y - d0], 1);
        srcs[csr0 + off] = (int)p.x;
    }
    if (b == 0 && t == 0) rowptr[n] = tot;
}

// --- tiled node GEMM: 64 nodes x 64 cols per block, 4x4 per thread ----------
template <int IN_DIM>
__global__ __launch_bounds__(256) void node_gemm(const float* __restrict__ x,
                                                 const float* __restrict__ W,
                                                 const float* __restrict__ a_src,
                                                 const float* __restrict__ a_dst,
                                                 const float* __restrict__ bias_in,
                                                 float slope_in,
                                                 unsigned short* __restrict__ h16,
                                                 float* __restrict__ al_s,
                                                 float* __restrict__ al_d,
                                                 int n) {
    __shared__ float Ws[IN_DIM * 64];
    __shared__ float xs[IN_DIM][64];   // [k][node] — conflict-free both ways
    int t = threadIdx.x;
    int nbase = blockIdx.x * 64;

    for (int idx = t; idx < IN_DIM * 16; idx += 256)
        ((float4*)Ws)[idx] = ((const float4*)W)[idx];
    for (int idx = t; idx < IN_DIM * 64; idx += 256) {
        int node = nbase + (idx & 63);
        int k = idx >> 6;
        float v = 0.0f;
        if (node < n) {
            v = x[(size_t)node * IN_DIM + k];
            if (bias_in) {
                v += bias_in[k];
                v = (v >= 0.0f) ? v : slope_in * v;
            }
        }
        xs[k][idx & 63] = v;
    }
    __syncthreads();

    int cg = t & 15;    // col group: cols 4cg..4cg+3
    int ng = t >> 4;    // node group: nodes 4ng..4ng+3
    float acc[4][4] = {};
#pragma unroll 8
    for (int k = 0; k < IN_DIM; k++) {
        float4 xv = *(const float4*)&xs[k][ng * 4];
        float4 wv = *(const float4*)&Ws[k * 64 + cg * 4];
        float xa[4] = {xv.x, xv.y, xv.z, xv.w};
        float wa[4] = {wv.x, wv.y, wv.z, wv.w};
#pragma unroll
        for (int i = 0; i < 4; i++)
#pragma unroll
            for (int j = 0; j < 4; j++)
                acc[i][j] += xa[i] * wa[j];
    }

    float4 as4 = *(const float4*)(a_src + cg * 4);
    float4 ad4 = *(const float4*)(a_dst + cg * 4);
#pragma unroll
    for (int i = 0; i < 4; i++) {
        int node = nbase + ng * 4 + i;
        if (node < n) {
            uint2 p;
            p.x = f2bf(acc[i][0]) | (f2bf(acc[i][1]) << 16);
            p.y = f2bf(acc[i][2]) | (f2bf(acc[i][3]) << 16);
            *(uint2*)(h16 + (size_t)node * 64 + cg * 4) = p;
        }
        float vs = acc[i][0] * as4.x + acc[i][1] * as4.y +
                   acc[i][2] * as4.z + acc[i][3] * as4.w;
        float vd = acc[i][0] * ad4.x + acc[i][1] * ad4.y +
                   acc[i][2] * ad4.z + acc[i][3] * ad4.w;
#pragma unroll
        for (int o = 8; o; o >>= 1) {
            vs += __shfl_xor(vs, o);
            vd += __shfl_xor(vd, o);
        }
        if (cg == 0 && node < n) { al_s[node] = vs; al_d[node] = vd; }
    }
}

// --- single-pass CSR aggregate: 8 lanes/node, uint4 bf16x8 loads, unroll 4 --
// out[node] = (sum_j exp(e_j) * h[src_j]) / (sum_j exp(e_j) + 1e-16)
// sm is accumulated redundantly per lane (identical values, no reduction).
__device__ __forceinline__ void bf8_fma(float* acc, uint4 q, float w) {
    acc[0] += w * __uint_as_float(q.x << 16);
    acc[1] += w * __uint_as_float(q.x & 0xFFFF0000u);
    acc[2] += w * __uint_as_float(q.y << 16);
    acc[3] += w * __uint_as_float(q.y & 0xFFFF0000u);
    acc[4] += w * __uint_as_float(q.z << 16);
    acc[5] += w * __uint_as_float(q.z & 0xFFFF0000u);
    acc[6] += w * __uint_as_float(q.w << 16);
    acc[7] += w * __uint_as_float(q.w & 0xFFFF0000u);
}

__global__ __launch_bounds__(256) void gat_aggregate(const int* __restrict__ rowptr,
                                                     const int* __restrict__ srcs,
                                                     const float* __restrict__ als,
                                                     const float* __restrict__ ald,
                                                     const unsigned short* __restrict__ h16,
                                                     float* __restrict__ hout,
                                                     int n) {
    int t = threadIdx.x;
    int sub = t >> 3, lane = t & 7;       // 32 nodes/block, 8 lanes/node
    int node = blockIdx.x * 32 + sub;
    if (node >= n) return;
    int beg = rowptr[node], end = rowptr[node + 1];
    float aldv = ald[node];

    float acc[8] = {};
    float sm = 0.0f;
    int j = beg;
    // unrolled x4: batch independent loads for MLP
    for (; j + 4 <= end; j += 4) {
        int s0 = srcs[j], s1 = srcs[j + 1], s2 = srcs[j + 2], s3 = srcs[j + 3];
        float e0 = als[s0] + aldv, e1 = als[s1] + aldv;
        float e2 = als[s2] + aldv, e3 = als[s3] + aldv;
        uint4 q0 = *(const uint4*)(h16 + (size_t)s0 * 64 + lane * 8);
        uint4 q1 = *(const uint4*)(h16 + (size_t)s1 * 64 + lane * 8);
        uint4 q2 = *(const uint4*)(h16 + (size_t)s2 * 64 + lane * 8);
        uint4 q3 = *(const uint4*)(h16 + (size_t)s3 * 64 + lane * 8);
        e0 = (e0 >= 0.0f) ? e0 : 0.2f * e0;
        e1 = (e1 >= 0.0f) ? e1 : 0.2f * e1;
        e2 = (e2 >= 0.0f) ? e2 : 0.2f * e2;
        e3 = (e3 >= 0.0f) ? e3 : 0.2f * e3;
        float w0 = __expf(e0), w1 = __expf(e1);
        float w2 = __expf(e2), w3 = __expf(e3);
        sm += (w0 + w1) + (w2 + w3);
        bf8_fma(acc, q0, w0);
        bf8_fma(acc, q1, w1);
        bf8_fma(acc, q2, w2);
        bf8_fma(acc, q3, w3);
    }
    for (; j < end; j++) {
        int s = srcs[j];
        float e = als[s] + aldv;
        e = (e >= 0.0f) ? e : 0.2f * e;
        float w = __expf(e);
        uint4 q = *(const uint4*)(h16 + (size_t)s * 64 + lane * 8);
        sm += w;
        bf8_fma(acc, q, w);
    }

    float inv = 1.0f / (sm + 1e-16f);
    float4 o0 = make_float4(acc[0] * inv, acc[1] * inv, acc[2] * inv, acc[3] * inv);
    float4 o1 = make_float4(acc[4] * inv, acc[5] * inv, acc[6] * inv, acc[7] * inv);
    float* op = hout + (size_t)node * 64 + lane * 8;
    *(float4*)op = o0;
    *(float4*)(op + 4) = o1;
}

// --- pooling: run-length accumulate over sorted batch, then one atomic ------
__global__ __launch_bounds__(256) void pool_run(const float* __restrict__ hout,
                                                const float* __restrict__ b2,
                                                const int* __restrict__ batch,
                                                float* __restrict__ pooled,
                                                float* __restrict__ cnt,
                                                int n) {
    int t = threadIdx.x;
    int wv = blockIdx.x * 4 + (t >> 6);
    int lane = t & 63;
    int start = wv * 64;
    if (start >= n) return;
    int end = min(start + 64, n);
    float bb = b2[lane];
    int gcur = batch[start];
    float acc = 0.0f;
    int rl = 0;
    for (int node = start; node < end; node++) {
        int g = batch[node];
        if (g != gcur) {
            atomAddF(&pooled[gcur * 64 + lane], acc);
            if (lane == 0) atomAddF(&cnt[gcur], (float)rl);
            acc = 0.0f; rl = 0; gcur = g;
        }
        acc += hout[(size_t)node * 64 + lane] + bb;
        rl++;
    }
    atomAddF(&pooled[gcur * 64 + lane], acc);
    if (lane == 0) atomAddF(&cnt[gcur], (float)rl);
}

// --- final FC: out[g] = (pooled[g]/max(cnt,1)) @ fcW + fcb ------------------
__global__ __launch_bounds__(64) void final_fc(const float* __restrict__ pooled,
                                               const float* __restrict__ cnt,
                                               const float* __restrict__ fcW,
                                               const float* __restrict__ fcb,
                                               float* __restrict__ out) {
    int g = blockIdx.x;
    int lane = threadIdx.x;
    float c = cnt[g];
    c = (c > 1.0f) ? c : 1.0f;
    float p = pooled[g * 64 + lane] / c;
    float s0 = p * fcW[lane * 2 + 0];
    float s1 = p * fcW[lane * 2 + 1];
#pragma unroll
    for (int o = 32; o; o >>= 1) {
        s0 += __shfl_xor(s0, o);
        s1 += __shfl_xor(s1, o);
    }
    if (lane == 0) {
        out[g * 2 + 0] = s0 + fcb[0];
        out[g * 2 + 1] = s1 + fcb[1];
    }
}

extern "C" void kernel_launch(void* const* d_in, const int* in_sizes, int n_in,
                              void* d_out, int out_size, void* d_ws, size_t ws_size,
                              hipStream_t stream) {
    const float* x    = (const float*)d_in[0];
    const int*   ei   = (const int*)d_in[1];
    const int*   batch= (const int*)d_in[2];
    const float* W1   = (const float*)d_in[3];
    const float* as1  = (const float*)d_in[4];
    const float* ad1  = (const float*)d_in[5];
    const float* b1   = (const float*)d_in[6];
    const float* W2   = (const float*)d_in[7];
    const float* as2  = (const float*)d_in[8];
    const float* ad2  = (const float*)d_in[9];
    const float* b2   = (const float*)d_in[10];
    const float* fcW  = (const float*)d_in[11];
    const float* fcb  = (const float*)d_in[12];
    float* out = (float*)d_out;

    const int N = in_sizes[2];       // 100000
    const int E = in_sizes[1] / 2;   // 1600000
    const int G = out_size / 2;      // 256
    const int tot = E + N;
    const int NB = (N + NPB - 1) / NPB;   // 391 buckets

    // ws layout (pairs needs 8B alignment: placed right after bufO)
    float* ws     = (float*)d_ws;
    float* bufO   = ws;                          // N*64 fp32
    uint2* pairs  = (uint2*)(bufO + (size_t)N * 64);          // E uint2
    float* als    = (float*)(pairs + E);         // N
    float* ald    = als + N;                     // N
    float* pooled = ald + N;                     // G*64
    float* cnt    = pooled + (size_t)G * 64;     // G
    int*   rowptr = (int*)(cnt + G);             // N+1
    int*   srcs   = rowptr + N + 1;              // E+N
    int*   bcnt   = srcs + tot;                  // NB
    int*   bbase  = bcnt + NB;                   // NB
    int*   bcur   = bbase + NB;                  // NB
    unsigned short* bufH16 = (unsigned short*)(bcur + NB);    // N*64 bf16

    dim3 b256(256);
    int gInit = (max(G * 64, NB) + 255) / 256;
    int gPart = (E + EPB - 1) / EPB;
    int gGemm = (N + 63) / 64;
    int gAgg  = (N + 31) / 32;
    int gPool = ((N + 63) / 64 + 3) / 4;

    // ---- CSR build via bucket partition (edge_index only) ----
    init_all<<<gInit, b256, 0, stream>>>(pooled, cnt, bcnt, NB, G);
    bucket_hist<<<gPart, b256, 0, stream>>>(ei, E, NB, bcnt);
    scan_buckets<<<1, 512, 0, stream>>>(bcnt, bbase, bcur, NB);
    partition<<<gPart, b256, 0, stream>>>(ei, E, NB, bcur, pairs);
    build_csr<<<NB, b256, 0, stream>>>(pairs, bcnt, bbase, N, tot, rowptr, srcs);

    // ---- layer 1 ----
    node_gemm<72><<<gGemm, b256, 0, stream>>>(x, W1, as1, ad1, nullptr, 0.0f,
                                              bufH16, als, ald, N);
    gat_aggregate<<<gAgg, b256, 0, stream>>>(rowptr, srcs, als, ald, bufH16, bufO, N);

    // ---- layer 2 (input = leaky(bufO + b1, 0.01)) ----
    node_gemm<64><<<gGemm, b256, 0, stream>>>(bufO, W2, as2, ad2, b1, 0.01f,
                                              bufH16, als, ald, N);
    gat_aggregate<<<gAgg, b256, 0, stream>>>(rowptr, srcs, als, ald, bufH16, bufO, N);

    // ---- pool + fc ----
    pool_run<<<gPool, b256, 0, stream>>>(bufO, b2, batch, pooled, cnt, N);
    final_fc<<<G, 64, 0, stream>>>(pooled, cnt, fcW, fcb, out);
}